// Round 1
// baseline (179.804 us; speedup 1.0000x reference)
//
#include <hip/hip_runtime.h>

#define D 300
#define KP 328          // padded K stride (elements) in ws and LDS rows (656 B, 16B-aligned)
#define KSTEPS 10       // 320 / 32
#define HDIM 512
#define WPB 32          // words per block
#define NSEG 41         // 41984 B per 64-row chunk / 1024 B segments

typedef __attribute__((ext_vector_type(4))) float f32x4;
typedef __attribute__((ext_vector_type(8))) short bf16x8;

__device__ inline unsigned short f2bf(float f) {
  unsigned int u = __float_as_uint(f);
  unsigned int r = (u + 0x7fffu + ((u >> 16) & 1u)) >> 16;
  return (unsigned short)r;
}

__device__ inline void gload_lds16(const void* g, void* l) {
  __builtin_amdgcn_global_load_lds(
      (const __attribute__((address_space(1))) unsigned int*)g,
      (__attribute__((address_space(3))) unsigned int*)l, 16, 0, 0);
}

// Transpose + pad + bf16-convert weights into ws: rows 0-511 = Wq cols, 512-1023 = Wk, 1024-1535 = Wv.
// wt[n][k] = W[k][n&511], zero for k >= 300.
__global__ __launch_bounds__(512) void prep_weights(
    const float* __restrict__ Wq, const float* __restrict__ Wk,
    const float* __restrict__ Wv, unsigned short* __restrict__ wt) {
  int idx = blockIdx.x * 512 + threadIdx.x;
  if (idx >= 1536 * KP) return;
  int n = idx / KP, k = idx - n * KP;
  const float* src = (n < 512) ? Wq : ((n < 1024) ? Wk : Wv);
  int col = n & 511;
  float v = (k < D) ? src[k * HDIM + col] : 0.0f;
  wt[idx] = f2bf(v);
}

__global__ __launch_bounds__(512) void fused_attn(
    const float* __restrict__ charv, const float* __restrict__ wordv,
    const unsigned short* __restrict__ wt,
    const float* __restrict__ bk, const float* __restrict__ bq,
    const float* __restrict__ bv, float* __restrict__ out) {
  extern __shared__ char lds[];
  unsigned short* Xl = (unsigned short*)lds;        // [64][KP] bf16, rows interleaved word/char
  char* WAc = lds + 41984;                          // [64][KP] bf16 chunk
  char* WBc = lds + 2 * 41984;                      // [64][KP] bf16 chunk
  float* sS  = (float*)(lds + 3 * 41984);           // [2][32][4] per-wcol score partials
  float* sAt = sS + 256;                            // [32][4] attn weights

  const int tid  = threadIdx.x;
  const int wid  = tid >> 6;
  const int lane = tid & 63;
  const int lrow = lane & 15;            // fragment row (A) / col (B,C)
  const int kslc = (lane >> 4) * 8;      // k-slice within 32
  const int wrow = wid >> 1;             // 0..3 : rows wrow*16
  const int wcol = wid & 1;              // 0..1 : cols wcol*32
  const int g0   = blockIdx.x * WPB;

  // ---- stage X tile: 64 rows x 300 f32 -> bf16 LDS (75 float4 per row)
  for (int i = tid; i < 64 * 75; i += 512) {
    int r = i / 75, c4 = i - r * 75;
    const float* src = (r & 1) ? charv : wordv;
    const float4 v = *(const float4*)(src + (g0 + (r >> 1)) * D + c4 * 4);
    ushort4 h;
    h.x = f2bf(v.x); h.y = f2bf(v.y); h.z = f2bf(v.z); h.w = f2bf(v.w);
    *(ushort4*)(Xl + r * KP + c4 * 4) = h;
  }
  for (int i = tid; i < 64 * 7; i += 512) {   // zero-pad cols 300..327
    int r = i / 7, j = i - r * 7;
    ushort4 z; z.x = z.y = z.z = z.w = 0;
    *(ushort4*)(Xl + r * KP + 300 + j * 4) = z;
  }

  // ---- Phase A: accumulate 2x2 scores per word across all 512 Q/K cols
  float p[8] = {0.f, 0.f, 0.f, 0.f, 0.f, 0.f, 0.f, 0.f};

  for (int hc = 0; hc < 8; ++hc) {
    __syncthreads();  // previous chunk consumed (and X stage done at hc=0)
    {
      const char* srcQ = (const char*)(wt + (hc * 64) * KP);
      const char* srcK = (const char*)(wt + (512 + hc * 64) * KP);
      for (int j = wid; j < 2 * NSEG; j += 8) {
        if (j < NSEG) gload_lds16(srcQ + j * 1024 + lane * 16, WAc + j * 1024);
        else          gload_lds16(srcK + (j - NSEG) * 1024 + lane * 16, WBc + (j - NSEG) * 1024);
      }
    }
    __syncthreads();

    f32x4 accQ[2], accK[2];
    for (int n = 0; n < 2; ++n) {
      int col = hc * 64 + wcol * 32 + n * 16 + lrow;
      float vq = bq[col], vk = bk[col];
      accQ[n] = (f32x4){vq, vq, vq, vq};
      accK[n] = (f32x4){vk, vk, vk, vk};
    }
    for (int ks = 0; ks < KSTEPS; ++ks) {
      const int ko = ks * 32 + kslc;
      bf16x8 a = *(const bf16x8*)(Xl + (wrow * 16 + lrow) * KP + ko);
      for (int n = 0; n < 2; ++n) {
        int c = wcol * 32 + n * 16 + lrow;
        bf16x8 fq = *(const bf16x8*)((const unsigned short*)WAc + c * KP + ko);
        bf16x8 fk = *(const bf16x8*)((const unsigned short*)WBc + c * KP + ko);
        accQ[n] = __builtin_amdgcn_mfma_f32_16x16x32_bf16(a, fq, accQ[n], 0, 0, 0);
        accK[n] = __builtin_amdgcn_mfma_f32_16x16x32_bf16(a, fk, accK[n], 0, 0, 0);
      }
    }
    // lane-local score partials: C-layout => same lane holds Q and K for same (word,col)
    for (int n = 0; n < 2; ++n)
      for (int w = 0; w < 2; ++w)
        for (int i = 0; i < 2; ++i)
          for (int j = 0; j < 2; ++j)
            p[w * 4 + i * 2 + j] += accQ[n][w * 2 + i] * accK[n][w * 2 + j];
  }

  // reduce over the 16 col-lanes (masks 1,2,4,8 stay within lane>>4 group)
  for (int t = 0; t < 8; ++t) {
    float v = p[t];
    v += __shfl_xor(v, 1);
    v += __shfl_xor(v, 2);
    v += __shfl_xor(v, 4);
    v += __shfl_xor(v, 8);
    p[t] = v;
  }
  if (lrow == 0) {
    int wA = wrow * 8 + (lane >> 4) * 2;  // local word of regs 0,1 (regs 2,3 -> wA+1)
    for (int t = 0; t < 8; ++t)
      sS[wcol * 128 + (wA + (t >> 2)) * 4 + (t & 3)] = p[t];
  }
  __syncthreads();

  if (tid < 32) {
    const float sc = 0.044194173824159216f;  // 1/sqrt(512)
    float s[4];
    for (int t = 0; t < 4; ++t) s[t] = (sS[tid * 4 + t] + sS[128 + tid * 4 + t]) * sc;
    for (int i = 0; i < 2; ++i) {
      float m  = fmaxf(s[i * 2], s[i * 2 + 1]);
      float e0 = expf(s[i * 2] - m), e1 = expf(s[i * 2 + 1] - m);
      float inv = 1.0f / (e0 + e1);
      sAt[tid * 4 + i * 2]     = e0 * inv;
      sAt[tid * 4 + i * 2 + 1] = e1 * inv;
    }
  }

  // ---- Phase B: V projection + attention-weighted combine (lane-local epilogue)
  for (int hc = 0; hc < 8; ++hc) {
    __syncthreads();  // also publishes sAt at hc=0
    {
      const char* srcV = (const char*)(wt + (1024 + hc * 64) * KP);
      for (int j = wid; j < NSEG; j += 8)
        gload_lds16(srcV + j * 1024 + lane * 16, WAc + j * 1024);
    }
    __syncthreads();

    f32x4 accV[2];
    for (int n = 0; n < 2; ++n) {
      int col = hc * 64 + wcol * 32 + n * 16 + lrow;
      float b = bv[col];
      accV[n] = (f32x4){b, b, b, b};
    }
    for (int ks = 0; ks < KSTEPS; ++ks) {
      const int ko = ks * 32 + kslc;
      bf16x8 a = *(const bf16x8*)(Xl + (wrow * 16 + lrow) * KP + ko);
      for (int n = 0; n < 2; ++n) {
        int c = wcol * 32 + n * 16 + lrow;
        bf16x8 fv = *(const bf16x8*)((const unsigned short*)WAc + c * KP + ko);
        accV[n] = __builtin_amdgcn_mfma_f32_16x16x32_bf16(a, fv, accV[n], 0, 0, 0);
      }
    }
    // regs 0..3 = rows 4g..4g+3 = words (wA: V0,V1), (wA+1: V0,V1)
    int wA = wrow * 8 + (lane >> 4) * 2;
    float a0[4], a1[4];
    for (int t = 0; t < 4; ++t) { a0[t] = sAt[wA * 4 + t]; a1[t] = sAt[(wA + 1) * 4 + t]; }
    int gA = g0 + wA;
    for (int n = 0; n < 2; ++n) {
      int h = hc * 64 + wcol * 32 + n * 16 + lrow;
      float* o = out + gA * 1024 + h;
      o[0]    = a0[0] * accV[n][0] + a0[1] * accV[n][1];
      o[512]  = a0[2] * accV[n][0] + a0[3] * accV[n][1];
      o[1024] = a1[0] * accV[n][2] + a1[1] * accV[n][3];
      o[1536] = a1[2] * accV[n][2] + a1[3] * accV[n][3];
    }
  }
}

extern "C" void kernel_launch(void* const* d_in, const int* in_sizes, int n_in,
                              void* d_out, int out_size, void* d_ws, size_t ws_size,
                              hipStream_t stream) {
  const float* charv = (const float*)d_in[0];
  const float* wordv = (const float*)d_in[1];
  const float* Wk = (const float*)d_in[2];
  const float* bk = (const float*)d_in[3];
  const float* Wq = (const float*)d_in[4];
  const float* bq = (const float*)d_in[5];
  const float* Wv = (const float*)d_in[6];
  const float* bv = (const float*)d_in[7];
  float* out = (float*)d_out;
  unsigned short* wt = (unsigned short*)d_ws;  // 1536*328*2 = 1,007,616 B

  prep_weights<<<(1536 * KP + 511) / 512, 512, 0, stream>>>(Wq, Wk, Wv, wt);

  const int lds_bytes = 3 * 41984 + 256 * 4 + 128 * 4;  // 127,488 B
  fused_attn<<<32768 / WPB, 512, lds_bytes, stream>>>(charv, wordv, wt, bk, bq, bv, out);
}

// Round 2
// 115.776 us; speedup vs baseline: 1.5530x; 1.5530x over previous
//
#include <hip/hip_runtime.h>

#define D 300
#define KP 328          // padded K stride (elements); 656 B rows, 16B-aligned
#define KSTEPS 10       // 320 / 32
#define HDIM 512
#define WPB 32          // words per block (64 X rows)
#define NSEG 41         // 64*KP*2 / 1024

typedef __attribute__((ext_vector_type(4))) float f32x4;
typedef __attribute__((ext_vector_type(8))) short bf16x8;

__device__ inline unsigned short f2bf(float f) {
  unsigned int u = __float_as_uint(f);
  unsigned int r = (u + 0x7fffu + ((u >> 16) & 1u)) >> 16;
  return (unsigned short)r;
}

__device__ inline void gload_lds16(const void* g, void* l) {
  __builtin_amdgcn_global_load_lds(
      (const __attribute__((address_space(1))) unsigned int*)g,
      (__attribute__((address_space(3))) unsigned int*)l, 16, 0, 0);
}

// wt[n][k] = W[k][n&511] bf16, rows 0-511=Wq, 512-1023=Wk, 1024-1535=Wv, k>=300 zero
__global__ __launch_bounds__(512) void prep_weights(
    const float* __restrict__ Wq, const float* __restrict__ Wk,
    const float* __restrict__ Wv, unsigned short* __restrict__ wt) {
  int idx = blockIdx.x * 512 + threadIdx.x;
  if (idx >= 1536 * KP) return;
  int n = idx / KP, k = idx - n * KP;
  const float* src = (n < 512) ? Wq : ((n < 1024) ? Wk : Wv);
  int col = n & 511;
  float v = (k < D) ? src[k * HDIM + col] : 0.0f;
  wt[idx] = f2bf(v);
}

__global__ __launch_bounds__(256) void fused_attn(
    const float* __restrict__ charv, const float* __restrict__ wordv,
    const unsigned short* __restrict__ wt,
    const float* __restrict__ bk, const float* __restrict__ bq,
    const float* __restrict__ bv, float* __restrict__ out) {
  extern __shared__ char lds[];
  unsigned short* buf = (unsigned short*)lds;   // [64][KP]: X tile, then weight chunks
  float* sS  = (float*)(lds + 41984);           // [2 cg][32 w][4]
  float* sAt = sS + 256;                        // [32 w][4]

  const int tid  = threadIdx.x;
  const int wid  = tid >> 6;
  const int lane = tid & 63;
  const int lrow = lane & 15;
  const int kgrp = lane >> 4;
  const int rg   = wid >> 1;   // row-group: rows rg*32 .. +32
  const int cg   = wid & 1;    // col-group: cols cg*32 .. +32 of the 64-col chunk
  const int g0   = blockIdx.x * WPB;

  // ---- stage X tile: 64 rows x 300 f32 -> bf16 LDS (rows interleaved word/char)
  for (int i = tid; i < 64 * 75; i += 256) {
    int r = i / 75, c4 = i - r * 75;
    const float* src = (r & 1) ? charv : wordv;
    const float4 v = *(const float4*)(src + (g0 + (r >> 1)) * D + c4 * 4);
    ushort4 h;
    h.x = f2bf(v.x); h.y = f2bf(v.y); h.z = f2bf(v.z); h.w = f2bf(v.w);
    *(ushort4*)(buf + r * KP + c4 * 4) = h;
  }
  for (int i = tid; i < 64 * 7; i += 256) {   // zero-pad cols 300..327
    int r = i / 7, j = i - r * 7;
    ushort4 z; z.x = z.y = z.z = z.w = 0;
    *(ushort4*)(buf + r * KP + 300 + j * 4) = z;
  }
  __syncthreads();

  // ---- A-fragments to registers, once: wave's 32 rows x 320 K
  bf16x8 a[2][KSTEPS];
#pragma unroll
  for (int rt = 0; rt < 2; ++rt)
#pragma unroll
    for (int ks = 0; ks < KSTEPS; ++ks)
      a[rt][ks] = *(const bf16x8*)(buf + (rg * 32 + rt * 16 + lrow) * KP + ks * 32 + kgrp * 8);

  float p[2][8];
#pragma unroll
  for (int rt = 0; rt < 2; ++rt)
#pragma unroll
    for (int t = 0; t < 8; ++t) p[rt][t] = 0.f;

  // ---- Phase A: per 64-col group, project Q then K, accumulate lane-local scores
  for (int g = 0; g < 8; ++g) {
    f32x4 accQ[2][2], accK[2][2];

    // Q chunk
    __syncthreads();   // prior buf use done (A-frag reads at g=0 / K compute at g>0)
    {
      const char* src = (const char*)(wt + (g * 64) * KP);
      for (int j = wid; j < NSEG; j += 4)
        gload_lds16(src + j * 1024 + lane * 16, (char*)buf + j * 1024);
    }
    __syncthreads();
#pragma unroll
    for (int rt = 0; rt < 2; ++rt)
#pragma unroll
      for (int ct = 0; ct < 2; ++ct) {
        float b = bq[g * 64 + cg * 32 + ct * 16 + lrow];
        accQ[rt][ct] = (f32x4){b, b, b, b};
      }
#pragma unroll
    for (int ks = 0; ks < KSTEPS; ++ks) {
      const unsigned short* bp = buf + cg * 32 * KP + ks * 32 + kgrp * 8;
      bf16x8 b0 = *(const bf16x8*)(bp + lrow * KP);
      bf16x8 b1 = *(const bf16x8*)(bp + (16 + lrow) * KP);
      accQ[0][0] = __builtin_amdgcn_mfma_f32_16x16x32_bf16(a[0][ks], b0, accQ[0][0], 0, 0, 0);
      accQ[1][0] = __builtin_amdgcn_mfma_f32_16x16x32_bf16(a[1][ks], b0, accQ[1][0], 0, 0, 0);
      accQ[0][1] = __builtin_amdgcn_mfma_f32_16x16x32_bf16(a[0][ks], b1, accQ[0][1], 0, 0, 0);
      accQ[1][1] = __builtin_amdgcn_mfma_f32_16x16x32_bf16(a[1][ks], b1, accQ[1][1], 0, 0, 0);
    }

    // K chunk
    __syncthreads();
    {
      const char* src = (const char*)(wt + (512 + g * 64) * KP);
      for (int j = wid; j < NSEG; j += 4)
        gload_lds16(src + j * 1024 + lane * 16, (char*)buf + j * 1024);
    }
    __syncthreads();
#pragma unroll
    for (int rt = 0; rt < 2; ++rt)
#pragma unroll
      for (int ct = 0; ct < 2; ++ct) {
        float b = bk[g * 64 + cg * 32 + ct * 16 + lrow];
        accK[rt][ct] = (f32x4){b, b, b, b};
      }
#pragma unroll
    for (int ks = 0; ks < KSTEPS; ++ks) {
      const unsigned short* bp = buf + cg * 32 * KP + ks * 32 + kgrp * 8;
      bf16x8 b0 = *(const bf16x8*)(bp + lrow * KP);
      bf16x8 b1 = *(const bf16x8*)(bp + (16 + lrow) * KP);
      accK[0][0] = __builtin_amdgcn_mfma_f32_16x16x32_bf16(a[0][ks], b0, accK[0][0], 0, 0, 0);
      accK[1][0] = __builtin_amdgcn_mfma_f32_16x16x32_bf16(a[1][ks], b0, accK[1][0], 0, 0, 0);
      accK[0][1] = __builtin_amdgcn_mfma_f32_16x16x32_bf16(a[0][ks], b1, accK[0][1], 0, 0, 0);
      accK[1][1] = __builtin_amdgcn_mfma_f32_16x16x32_bf16(a[1][ks], b1, accK[1][1], 0, 0, 0);
    }

    // lane-local score partials (same lane holds Q and K for same (word,col))
#pragma unroll
    for (int rt = 0; rt < 2; ++rt)
#pragma unroll
      for (int ct = 0; ct < 2; ++ct)
#pragma unroll
        for (int wl = 0; wl < 2; ++wl)
#pragma unroll
          for (int i = 0; i < 2; ++i)
#pragma unroll
            for (int j = 0; j < 2; ++j)
              p[rt][wl * 4 + i * 2 + j] += accQ[rt][ct][wl * 2 + i] * accK[rt][ct][wl * 2 + j];
  }

  // reduce over the 16 col-lanes
#pragma unroll
  for (int rt = 0; rt < 2; ++rt)
#pragma unroll
    for (int t = 0; t < 8; ++t) {
      float v = p[rt][t];
      v += __shfl_xor(v, 1);
      v += __shfl_xor(v, 2);
      v += __shfl_xor(v, 4);
      v += __shfl_xor(v, 8);
      p[rt][t] = v;
    }
  if (lrow == 0) {
#pragma unroll
    for (int rt = 0; rt < 2; ++rt)
#pragma unroll
      for (int t = 0; t < 8; ++t) {
        int w = rg * 16 + rt * 8 + kgrp * 2 + (t >> 2);
        sS[cg * 128 + w * 4 + (t & 3)] = p[rt][t];
      }
  }
  __syncthreads();

  if (tid < 32) {
    const float sc = 0.044194173824159216f;  // 1/sqrt(512)
    float s[4];
#pragma unroll
    for (int t = 0; t < 4; ++t) s[t] = (sS[tid * 4 + t] + sS[128 + tid * 4 + t]) * sc;
#pragma unroll
    for (int i = 0; i < 2; ++i) {
      float m  = fmaxf(s[i * 2], s[i * 2 + 1]);
      float e0 = expf(s[i * 2] - m), e1 = expf(s[i * 2 + 1] - m);
      float inv = 1.0f / (e0 + e1);
      sAt[tid * 4 + i * 2]     = e0 * inv;
      sAt[tid * 4 + i * 2 + 1] = e1 * inv;
    }
  }
  __syncthreads();

  // attention weights to registers (constant across V chunks)
  float at0[2][4], at1[2][4];
#pragma unroll
  for (int rt = 0; rt < 2; ++rt) {
    int wA = rg * 16 + rt * 8 + kgrp * 2;
#pragma unroll
    for (int t = 0; t < 4; ++t) {
      at0[rt][t] = sAt[wA * 4 + t];
      at1[rt][t] = sAt[(wA + 1) * 4 + t];
    }
  }

  // ---- Phase B: V projection + attention combine
  for (int g = 0; g < 8; ++g) {
    __syncthreads();
    {
      const char* src = (const char*)(wt + (1024 + g * 64) * KP);
      for (int j = wid; j < NSEG; j += 4)
        gload_lds16(src + j * 1024 + lane * 16, (char*)buf + j * 1024);
    }
    __syncthreads();

    f32x4 accV[2][2];
#pragma unroll
    for (int rt = 0; rt < 2; ++rt)
#pragma unroll
      for (int ct = 0; ct < 2; ++ct) {
        float b = bv[g * 64 + cg * 32 + ct * 16 + lrow];
        accV[rt][ct] = (f32x4){b, b, b, b};
      }
#pragma unroll
    for (int ks = 0; ks < KSTEPS; ++ks) {
      const unsigned short* bp = buf + cg * 32 * KP + ks * 32 + kgrp * 8;
      bf16x8 b0 = *(const bf16x8*)(bp + lrow * KP);
      bf16x8 b1 = *(const bf16x8*)(bp + (16 + lrow) * KP);
      accV[0][0] = __builtin_amdgcn_mfma_f32_16x16x32_bf16(a[0][ks], b0, accV[0][0], 0, 0, 0);
      accV[1][0] = __builtin_amdgcn_mfma_f32_16x16x32_bf16(a[1][ks], b0, accV[1][0], 0, 0, 0);
      accV[0][1] = __builtin_amdgcn_mfma_f32_16x16x32_bf16(a[0][ks], b1, accV[0][1], 0, 0, 0);
      accV[1][1] = __builtin_amdgcn_mfma_f32_16x16x32_bf16(a[1][ks], b1, accV[1][1], 0, 0, 0);
    }

#pragma unroll
    for (int rt = 0; rt < 2; ++rt) {
      int wA = rg * 16 + rt * 8 + kgrp * 2;
      int gA = g0 + wA;
#pragma unroll
      for (int ct = 0; ct < 2; ++ct) {
        int h = g * 64 + cg * 32 + ct * 16 + lrow;
        float* o = out + gA * 1024 + h;
        o[0]    = at0[rt][0] * accV[rt][ct][0] + at0[rt][1] * accV[rt][ct][1];
        o[512]  = at0[rt][2] * accV[rt][ct][0] + at0[rt][3] * accV[rt][ct][1];
        o[1024] = at1[rt][0] * accV[rt][ct][2] + at1[rt][1] * accV[rt][ct][3];
        o[1536] = at1[rt][2] * accV[rt][ct][2] + at1[rt][3] * accV[rt][ct][3];
      }
    }
  }
}

extern "C" void kernel_launch(void* const* d_in, const int* in_sizes, int n_in,
                              void* d_out, int out_size, void* d_ws, size_t ws_size,
                              hipStream_t stream) {
  const float* charv = (const float*)d_in[0];
  const float* wordv = (const float*)d_in[1];
  const float* Wk = (const float*)d_in[2];
  const float* bk = (const float*)d_in[3];
  const float* Wq = (const float*)d_in[4];
  const float* bq = (const float*)d_in[5];
  const float* Wv = (const float*)d_in[6];
  const float* bv = (const float*)d_in[7];
  float* out = (float*)d_out;
  unsigned short* wt = (unsigned short*)d_ws;  // 1536*328*2 B

  prep_weights<<<(1536 * KP + 511) / 512, 512, 0, stream>>>(Wq, Wk, Wv, wt);

  const int lds_bytes = 41984 + 256 * 4 + 128 * 4;  // 43,520 B
  fused_attn<<<32768 / WPB, 256, lds_bytes, stream>>>(charv, wordv, wt, bk, bq, bv, out);
}

// Round 3
// 98.158 us; speedup vs baseline: 1.8318x; 1.1795x over previous
//
#include <hip/hip_runtime.h>

#define D 300
#define KP 328          // padded K stride (elements); 656 B rows, bank stagger 4
#define KSTEPS 10       // 320 / 32
#define WPB 64          // words per block
#define ROWS 128        // X rows per block
#define NSEG 41         // 64*KP*2 / 1024
#define CHUNK_BYTES 41984

typedef __attribute__((ext_vector_type(4))) float f32x4;
typedef __attribute__((ext_vector_type(8))) short bf16x8;

__device__ inline unsigned short f2bf(float f) {
  unsigned int u = __float_as_uint(f);
  unsigned int r = (u + 0x7fffu + ((u >> 16) & 1u)) >> 16;
  return (unsigned short)r;
}

__device__ inline void gload_lds16(const void* g, void* l) {
  __builtin_amdgcn_global_load_lds(
      (const __attribute__((address_space(1))) unsigned int*)g,
      (__attribute__((address_space(3))) unsigned int*)l, 16, 0, 0);
}

// wt[n][k] = W[k][n&511] bf16; rows 0-511=Wq, 512-1023=Wk, 1024-1535=Wv; k>=300 zero
__global__ __launch_bounds__(512) void prep_weights(
    const float* __restrict__ Wq, const float* __restrict__ Wk,
    const float* __restrict__ Wv, unsigned short* __restrict__ wt) {
  int idx = blockIdx.x * 512 + threadIdx.x;
  if (idx >= 1536 * KP) return;
  int n = idx / KP, k = idx - n * KP;
  const float* src = (n < 512) ? Wq : ((n < 1024) ? Wk : Wv);
  int col = n & 511;
  float v = (k < D) ? src[k * 512 + col] : 0.0f;
  wt[idx] = f2bf(v);
}

__device__ __forceinline__ void proj_chunk(
    const unsigned short* __restrict__ bufp, const float* __restrict__ biasL,
    int nbase, int cg, int lrow, int kgrp,
    const bf16x8 (&a)[2][KSTEPS], f32x4 (&acc)[2][2]) {
#pragma unroll
  for (int rt = 0; rt < 2; ++rt)
#pragma unroll
    for (int ct = 0; ct < 2; ++ct) {
      float b = biasL[nbase + cg * 32 + ct * 16 + lrow];
      acc[rt][ct] = (f32x4){b, b, b, b};
    }
#pragma unroll
  for (int ks = 0; ks < KSTEPS; ++ks) {
    const unsigned short* bp = bufp + cg * 32 * KP + ks * 32 + kgrp * 8;
    bf16x8 b0 = *(const bf16x8*)(bp + lrow * KP);
    bf16x8 b1 = *(const bf16x8*)(bp + (16 + lrow) * KP);
    acc[0][0] = __builtin_amdgcn_mfma_f32_16x16x32_bf16(a[0][ks], b0, acc[0][0], 0, 0, 0);
    acc[1][0] = __builtin_amdgcn_mfma_f32_16x16x32_bf16(a[1][ks], b0, acc[1][0], 0, 0, 0);
    acc[0][1] = __builtin_amdgcn_mfma_f32_16x16x32_bf16(a[0][ks], b1, acc[0][1], 0, 0, 0);
    acc[1][1] = __builtin_amdgcn_mfma_f32_16x16x32_bf16(a[1][ks], b1, acc[1][1], 0, 0, 0);
  }
}

__global__ __launch_bounds__(512, 2) void fused_attn(
    const float* __restrict__ charv, const float* __restrict__ wordv,
    const unsigned short* __restrict__ wt,
    const float* __restrict__ bk, const float* __restrict__ bq,
    const float* __restrict__ bv, float* __restrict__ out) {
  extern __shared__ char lds[];
  float* biasL = (float*)(lds + 2 * CHUNK_BYTES);  // [1536]
  float* sS    = biasL + 1536;                     // [2 cg][64 w][4]
  float* sAt   = sS + 512;                         // [64 w][4]

  const int tid  = threadIdx.x;
  const int wid  = tid >> 6;
  const int lane = tid & 63;
  const int lrow = lane & 15;
  const int kgrp = lane >> 4;
  const int rg   = wid >> 1;   // 0..3 : rows rg*32..+32
  const int cg   = wid & 1;    // 0..1 : cols cg*32..+32 of the 64-col chunk

  // chunk t in 0..23: row base in wt (and in biasL)
  auto chunk_n = [](int t) {
    return (t < 16) ? ((t & 1) * 512 + (t >> 1) * 64) : (1024 + (t - 16) * 64);
  };
  auto stage = [&](int t) {
    const char* src = (const char*)(wt + chunk_n(t) * KP);
    char* dst = lds + (t & 1) * CHUNK_BYTES;
    for (int j = wid; j < NSEG; j += 8)
      gload_lds16(src + j * 1024 + lane * 16, dst + j * 1024);
  };

  // ---- prologue: stage chunk 0, biases -> LDS, A-fragments global -> regs
  stage(0);
  for (int i = tid; i < 1536; i += 512) {
    float v = (i < 512) ? bq[i] : ((i < 1024) ? bk[i - 512] : bv[i - 1024]);
    biasL[i] = v;
  }

  bf16x8 a[2][KSTEPS];
#pragma unroll
  for (int rt = 0; rt < 2; ++rt) {
    int row = blockIdx.x * ROWS + rg * 32 + rt * 16 + lrow;
    const float* rp = ((row & 1) ? charv : wordv) + (row >> 1) * D;
#pragma unroll
    for (int ks = 0; ks < KSTEPS; ++ks) {
      int k0 = ks * 32 + kgrp * 8;
      float4 lo = {0.f, 0.f, 0.f, 0.f}, hi = {0.f, 0.f, 0.f, 0.f};
      if (k0 + 8 <= D) {
        lo = *(const float4*)(rp + k0);
        hi = *(const float4*)(rp + k0 + 4);
      } else if (k0 < D) {
        lo = *(const float4*)(rp + k0);
      }
      bf16x8 v;
      v[0] = (short)f2bf(lo.x); v[1] = (short)f2bf(lo.y);
      v[2] = (short)f2bf(lo.z); v[3] = (short)f2bf(lo.w);
      v[4] = (short)f2bf(hi.x); v[5] = (short)f2bf(hi.y);
      v[6] = (short)f2bf(hi.z); v[7] = (short)f2bf(hi.w);
      a[rt][ks] = v;
    }
  }
  __syncthreads();  // chunk 0 landed, biases visible

  float p[2][8];
#pragma unroll
  for (int rt = 0; rt < 2; ++rt)
#pragma unroll
    for (int t = 0; t < 8; ++t) p[rt][t] = 0.f;

  // ---- Phase A: 16 sub-phases (Q_g, K_g interleaved), 2-phase pipeline
  int tg = 0;
  for (int g = 0; g < 8; ++g) {
    f32x4 accQ[2][2], accK[2][2];

    stage(tg + 1);  // K_g into other buffer, lands during Q compute
    proj_chunk((const unsigned short*)(lds + (tg & 1) * CHUNK_BYTES), biasL,
               g * 64, cg, lrow, kgrp, a, accQ);
    __syncthreads(); ++tg;

    stage(tg + 1);  // Q_{g+1} (or V_0 at g=7)
    proj_chunk((const unsigned short*)(lds + (tg & 1) * CHUNK_BYTES), biasL,
               512 + g * 64, cg, lrow, kgrp, a, accK);
    // lane-local score partials (same lane holds Q and K for same (word,col))
#pragma unroll
    for (int rt = 0; rt < 2; ++rt)
#pragma unroll
      for (int ct = 0; ct < 2; ++ct)
#pragma unroll
        for (int wl = 0; wl < 2; ++wl)
#pragma unroll
          for (int i = 0; i < 2; ++i)
#pragma unroll
            for (int j = 0; j < 2; ++j)
              p[rt][wl * 4 + i * 2 + j] += accQ[rt][ct][wl * 2 + i] * accK[rt][ct][wl * 2 + j];
    __syncthreads(); ++tg;
  }

  // ---- scores: reduce over 16 col-lanes, softmax (V_0 stage already in flight)
#pragma unroll
  for (int rt = 0; rt < 2; ++rt)
#pragma unroll
    for (int t = 0; t < 8; ++t) {
      float v = p[rt][t];
      v += __shfl_xor(v, 1);
      v += __shfl_xor(v, 2);
      v += __shfl_xor(v, 4);
      v += __shfl_xor(v, 8);
      p[rt][t] = v;
    }
  if (lrow == 0) {
#pragma unroll
    for (int rt = 0; rt < 2; ++rt)
#pragma unroll
      for (int t = 0; t < 8; ++t) {
        int w = rg * 16 + rt * 8 + kgrp * 2 + (t >> 2);
        sS[cg * 256 + w * 4 + (t & 3)] = p[rt][t];
      }
  }
  __syncthreads();
  if (tid < 64) {
    const float sc = 0.044194173824159216f;  // 1/sqrt(512)
    float s[4];
#pragma unroll
    for (int t = 0; t < 4; ++t) s[t] = (sS[tid * 4 + t] + sS[256 + tid * 4 + t]) * sc;
#pragma unroll
    for (int i = 0; i < 2; ++i) {
      float m  = fmaxf(s[i * 2], s[i * 2 + 1]);
      float e0 = expf(s[i * 2] - m), e1 = expf(s[i * 2 + 1] - m);
      float inv = 1.0f / (e0 + e1);
      sAt[tid * 4 + i * 2]     = e0 * inv;
      sAt[tid * 4 + i * 2 + 1] = e1 * inv;
    }
  }
  __syncthreads();

  float at0[2][4], at1[2][4];
#pragma unroll
  for (int rt = 0; rt < 2; ++rt) {
    int wA = rg * 16 + rt * 8 + kgrp * 2;
#pragma unroll
    for (int t = 0; t < 4; ++t) {
      at0[rt][t] = sAt[wA * 4 + t];
      at1[rt][t] = sAt[(wA + 1) * 4 + t];
    }
  }

  // ---- Phase B: V projection + attention combine, same pipeline
  for (int g = 0; g < 8; ++g) {
    if (tg + 1 < 24) stage(tg + 1);
    f32x4 accV[2][2];
    proj_chunk((const unsigned short*)(lds + (tg & 1) * CHUNK_BYTES), biasL,
               1024 + g * 64, cg, lrow, kgrp, a, accV);

#pragma unroll
    for (int rt = 0; rt < 2; ++rt) {
      int wA = rg * 16 + rt * 8 + kgrp * 2;
      int gA = blockIdx.x * WPB + wA;
#pragma unroll
      for (int ct = 0; ct < 2; ++ct) {
        int h = g * 64 + cg * 32 + ct * 16 + lrow;
        float* o = out + gA * 1024 + h;
        o[0]    = at0[rt][0] * accV[rt][ct][0] + at0[rt][1] * accV[rt][ct][1];
        o[512]  = at0[rt][2] * accV[rt][ct][0] + at0[rt][3] * accV[rt][ct][1];
        o[1024] = at1[rt][0] * accV[rt][ct][2] + at1[rt][1] * accV[rt][ct][3];
        o[1536] = at1[rt][2] * accV[rt][ct][2] + at1[rt][3] * accV[rt][ct][3];
      }
    }
    if (g < 7) __syncthreads();
    ++tg;
  }
}

extern "C" void kernel_launch(void* const* d_in, const int* in_sizes, int n_in,
                              void* d_out, int out_size, void* d_ws, size_t ws_size,
                              hipStream_t stream) {
  const float* charv = (const float*)d_in[0];
  const float* wordv = (const float*)d_in[1];
  const float* Wk = (const float*)d_in[2];
  const float* bk = (const float*)d_in[3];
  const float* Wq = (const float*)d_in[4];
  const float* bq = (const float*)d_in[5];
  const float* Wv = (const float*)d_in[6];
  const float* bv = (const float*)d_in[7];
  float* out = (float*)d_out;
  unsigned short* wt = (unsigned short*)d_ws;  // 1536*328*2 B

  prep_weights<<<(1536 * KP + 511) / 512, 512, 0, stream>>>(Wq, Wk, Wv, wt);

  const int lds_bytes = 2 * CHUNK_BYTES + 1536 * 4 + 512 * 4 + 256 * 4;  // 93,184 B
  fused_attn<<<32768 / WPB, 512, lds_bytes, stream>>>(charv, wordv, wt, bk, bq, bv, out);
}